// Round 2
// baseline (362.865 us; speedup 1.0000x reference)
//
#include <hip/hip_runtime.h>
#include <hip/hip_bf16.h>
#include <stdint.h>

typedef __bf16 bf16_t;
typedef bf16_t bf16x8 __attribute__((ext_vector_type(8)));
typedef bf16_t bf16x2 __attribute__((ext_vector_type(2)));
typedef float f32x4 __attribute__((ext_vector_type(4)));

#define E_N 65536
#define T_N 262144
#define CAP 16          // bucket capacity per edge (avg occupancy 4)
#define OVF_MAX T_N     // overflow list can hold every triplet -> always correct

#define ESET_BYTES 61440   // [Wkj img 32768][Wdown img 16384][Wcb img 10240][bias 512][pad]
#define PSET_BYTES 36864   // [W img 32768][bias 512][pad]

__device__ __forceinline__ float silu_f(float v) {
  return v / (1.0f + __expf(-v));
}

// B-row permutation: LDS row r = tj*16+i holds real output column
// 32*(tj>>1) + 2*i + (tj&1), so each lane's acc[2g],acc[2g+1] are 2
// consecutive real columns -> bf16x2 stores everywhere.
__device__ __forceinline__ int permrow(int n) {
  return (n & ~31) | ((n & 1) << 4) | ((n & 30) >> 1);
}

__device__ __forceinline__ uint32_t pack_bf16(float a, float b) {
  union { bf16x2 h; uint32_t u; } u;
  u.h[0] = (bf16_t)a; u.h[1] = (bf16_t)b;
  return u.u;
}

// ---- async global->LDS DMA (16B per lane, 1KB per wave-issue) ----
__device__ __forceinline__ void g2l16(const void* g, void* l) {
  __builtin_amdgcn_global_load_lds(
      (const __attribute__((address_space(1))) void*)g,
      (__attribute__((address_space(3))) void*)l, 16, 0, 0);
}

// Copy CHUNKS x 1KB from global to LDS; CHUNKS multiple of 4 (per-wave = CHUNKS/4).
template<int CHUNKS>
__device__ __forceinline__ void dma_copy(const char* g, char* l, int wv, int lane) {
#pragma unroll
  for (int c = 0; c < CHUNKS / 4; ++c) {
    const int off = (c * 4 + wv) * 1024 + lane * 16;
    g2l16(g + off, l + off);
  }
}

#define VMCNT0()  asm volatile("s_waitcnt vmcnt(0)" ::: "memory")

// ---- MFMA tile GEMM on swizzled stride-128 LDS tiles ----
// element (row,k) stored at row*128 + (((k>>3) ^ (row&15))<<3) + (k&7)
template<int KI, int NTJ>
__device__ __forceinline__ void gemm_tile(const bf16_t* A, const bf16_t* B,
                                          int mb, int nb, int l16, int q,
                                          f32x4 (&acc)[2][NTJ]) {
#pragma unroll
  for (int kt = 0; kt < KI; ++kt) {
    const int sw = ((kt * 4 + q) ^ l16) << 3;
    bf16x8 a0 = *(const bf16x8*)(A + ((mb + l16) << 7) + sw);
    bf16x8 a1 = *(const bf16x8*)(A + ((mb + 16 + l16) << 7) + sw);
#pragma unroll
    for (int tj = 0; tj < NTJ; ++tj) {
      bf16x8 b = *(const bf16x8*)(B + ((nb + tj * 16 + l16) << 7) + sw);
      acc[0][tj] = __builtin_amdgcn_mfma_f32_16x16x32_bf16(a0, b, acc[0][tj], 0, 0, 0);
      acc[1][tj] = __builtin_amdgcn_mfma_f32_16x16x32_bf16(a1, b, acc[1][tj], 0, 0, 0);
    }
  }
}

// Stage fp32 [rows][K] tile -> swizzled bf16 LDS. C4 = K/4.
template<int C4>
__device__ __forceinline__ void stage_x(bf16_t* dst, const float* src, int tid) {
  const float4* g = (const float4*)src;
#pragma unroll
  for (int i = tid; i < 64 * C4; i += 256) {
    const int row = i / C4, c4 = i % C4;
    float4 v = g[i];
    bf16_t t[4] = {(bf16_t)v.x, (bf16_t)v.y, (bf16_t)v.z, (bf16_t)v.w};
    *(uint2*)(dst + (row << 7) + ((((c4 >> 1) ^ (row & 15)) << 3) | ((c4 & 1) << 2))) =
        *(const uint2*)t;
  }
}

// =====================  K0: weight preprocessing  =====================
// Writes every weight in its final LDS-image layout (perm'd row + swizzled
// k-chunks) packed into DMA-able sets: 6 edge sets + 6 epi sets.
__global__ void prep_kernel(
    const float* __restrict__ W_ji, const float* __restrict__ W_kj,
    const float* __restrict__ W_down, const float* __restrict__ W_up,
    const float* __restrict__ rb1, const float* __restrict__ rb2,
    const float* __restrict__ W_lin, const float* __restrict__ ra1,
    const float* __restrict__ ra2, const float* __restrict__ W_rbf1,
    const float* __restrict__ W_rbf2,
    const float* __restrict__ b_ji, const float* __restrict__ b_kj,
    const float* __restrict__ rb1_b, const float* __restrict__ rb2_b,
    const float* __restrict__ b_lin, const float* __restrict__ ra1_b,
    const float* __restrict__ ra2_b,
    char* __restrict__ esets, char* __restrict__ psets)
{
  const int tid = threadIdx.x;
  const int blk = blockIdx.x;

  if (blk < 88) {          // 11 x [128x128] transposed images
    const int item = blk * 256 + tid;
    const int m = item >> 11, w = item & 2047;
    const int n = w >> 4, k8 = w & 15;
    const float* src; char* img;
    if (m == 0)      { src = W_ji;             img = esets; }
    else if (m <= 5) { src = W_kj + m * 16384; img = esets + m * ESET_BYTES; }
    else if (m == 6) { src = rb1;   img = psets + 1 * PSET_BYTES; }
    else if (m == 7) { src = rb2;   img = psets + 2 * PSET_BYTES; }
    else if (m == 8) { src = W_lin; img = psets + 3 * PSET_BYTES; }
    else if (m == 9) { src = ra1;   img = psets + 4 * PSET_BYTES; }
    else             { src = ra2;   img = psets + 5 * PSET_BYTES; }
    bf16_t t[8];
#pragma unroll
    for (int j = 0; j < 8; ++j) t[j] = (bf16_t)src[(k8 * 8 + j) * 128 + n];
    const int row = permrow(n);
    *(uint4*)((bf16_t*)img + (row << 7) + ((k8 ^ (row & 15)) << 3)) = *(const uint4*)t;
  } else if (blk < 108) {  // 5 x Wdown [64x128] images
    const int item = (blk - 88) * 256 + tid;
    const int m = item >> 10, w = item & 1023;
    const int n = w >> 4, k8 = w & 15;
    const float* src = W_down + (m + 1) * 8192;
    bf16_t* img = (bf16_t*)(esets + (m + 1) * ESET_BYTES + 32768);
    bf16_t t[8];
#pragma unroll
    for (int j = 0; j < 8; ++j) t[j] = (bf16_t)src[(k8 * 8 + j) * 64 + n];
    const int row = permrow(n);
    *(uint4*)(img + (row << 7) + ((k8 ^ (row & 15)) << 3)) = *(const uint4*)t;
  } else if (blk < 112) {  // wup [128 rows, K=64] image
    const int item = (blk - 108) * 256 + tid;
    const int n = item >> 3, k8 = item & 7;
    bf16_t t[8];
#pragma unroll
    for (int j = 0; j < 8; ++j) t[j] = (bf16_t)W_up[(k8 * 8 + j) * 128 + n];
    const int row = permrow(n);
    *(uint4*)((bf16_t*)psets + (row << 7) + ((k8 ^ (row & 15)) << 3)) = *(const uint4*)t;
  } else if (blk < 115) {  // fused W_rbf1@W_rbf2 -> Wcb images (stride-40, zero-padded)
    const int o = (blk - 112) * 256 + tid;
    if (o < 640) {
      const int b = o >> 7, n = o & 127;
      bf16_t t[8];
#pragma unroll
      for (int r = 0; r < 6; ++r) {
        const float* w1 = W_rbf1 + (b + 1) * 48 + r * 8;
        const float* w2 = W_rbf2 + (b + 1) * 1024 + n;
        float s = 0.f;
#pragma unroll
        for (int c = 0; c < 8; ++c) s += w1[c] * w2[c * 128];
        t[r] = (bf16_t)s;
      }
      t[6] = (bf16_t)0.f; t[7] = (bf16_t)0.f;
      bf16_t* img = (bf16_t*)(esets + (b + 1) * ESET_BYTES + 49152);
      const int row = permrow(n);
      const uint4 z = {0, 0, 0, 0};
      *(uint4*)(img + row * 40)      = *(const uint4*)t;
      *(uint4*)(img + row * 40 + 8)  = z;
      *(uint4*)(img + row * 40 + 16) = z;
      *(uint4*)(img + row * 40 + 24) = z;
    }
  } else {                 // biases into set tails
    const int n = tid & 127;
    for (int v = (tid >> 7); v < 11; v += 2) {
      float val; char* dst;
      if (v == 0)      { val = b_ji[n];          dst = esets + 59392; }
      else if (v <= 5) { val = b_kj[v * 128 + n]; dst = esets + v * ESET_BYTES + 59392; }
      else {
        const float* bs = (v == 6) ? rb1_b : (v == 7) ? rb2_b :
                          (v == 8) ? b_lin : (v == 9) ? ra1_b : ra2_b;
        val = bs[n]; dst = psets + (v - 5) * PSET_BYTES + 32768;
      }
      ((float*)dst)[n] = val;
    }
  }
}

// =====================  K1: branch-fused edge GEMMs  =====================
// One block per 64-row tile; x staged ONCE; 6 branches looped with
// double-buffered async-DMA weight sets (prefetch distance = 1 branch).
__global__ __launch_bounds__(256, 1)
void edge_kernel(const float* __restrict__ x, const float* __restrict__ rbf,
                 const char* __restrict__ esets,
                 bf16_t* __restrict__ x_ji_out, bf16_t* __restrict__ down)
{
  __shared__ __align__(16) bf16_t xA[64 * 128];      // 16384 B
  __shared__ __align__(16) bf16_t tmpA[64 * 128];    // 16384 B
  __shared__ __align__(16) bf16_t rbfA[64 * 40];     // 5120 B
  __shared__ __align__(16) char Wset[2][ESET_BYTES]; // 122880 B  (total 160768)

  const int tid = threadIdx.x;
  const int lane = tid & 63, wv = tid >> 6;
  const int q = lane >> 4, l16 = lane & 15;
  const int mb = (wv >> 1) * 32, nb = (wv & 1) * 64;
  const int R = blockIdx.x * 64;

  // stage x tile (fp32 -> swizzled bf16) -- once per block
  stage_x<32>(xA, x + (size_t)R * 128, tid);
  // stage rbf A-tile (wave 0), zero-padded to K=32
  if (tid < 64) {
    const float* rg = rbf + (size_t)(R + tid) * 6;
    bf16_t t[8] = {(bf16_t)rg[0], (bf16_t)rg[1], (bf16_t)rg[2],
                   (bf16_t)rg[3], (bf16_t)rg[4], (bf16_t)rg[5],
                   (bf16_t)0.f, (bf16_t)0.f};
    const uint4 z = {0, 0, 0, 0};
    *(uint4*)(rbfA + tid * 40)      = *(const uint4*)t;
    *(uint4*)(rbfA + tid * 40 + 8)  = z;
    *(uint4*)(rbfA + tid * 40 + 16) = z;
    *(uint4*)(rbfA + tid * 40 + 24) = z;
  }
  VMCNT0();   // clean vmcnt baseline before counted DMA waits
  dma_copy<60>(esets,              (char*)Wset[0], wv, lane);
  dma_copy<60>(esets + ESET_BYTES, (char*)Wset[1], wv, lane);
  asm volatile("s_waitcnt vmcnt(15)" ::: "memory");  // set0 landed (set1 in flight)
  __syncthreads();

  for (int br = 0; br < 6; ++br) {
    const char* slot = Wset[br & 1];
    const bf16_t* Wm  = (const bf16_t*)slot;            // Wji (br=0) / Wkj (br>=1)
    const bf16_t* Wdn = (const bf16_t*)(slot + 32768);
    const bf16_t* Wcb = (const bf16_t*)(slot + 49152);
    const float* biasS = (const float*)(slot + 59392);

    f32x4 acc[2][4] = {};
    gemm_tile<4, 4>(xA, Wm, mb, nb, l16, q, acc);

    if (br == 0) {
#pragma unroll
      for (int ti = 0; ti < 2; ++ti)
#pragma unroll
        for (int r = 0; r < 4; ++r) {
          const int row = mb + ti * 16 + q * 4 + r;
#pragma unroll
          for (int gl = 0; gl < 2; ++gl) {
            const int col0 = nb + gl * 32 + 2 * l16;
            const float2 b2 = *(const float2*)&biasS[col0];
            *(uint32_t*)&x_ji_out[(size_t)(R + row) * 128 + col0] =
                pack_bf16(silu_f(acc[ti][2 * gl][r] + b2.x),
                          silu_f(acc[ti][2 * gl + 1][r] + b2.y));
          }
        }
    } else {
      // rbf_p = rbf @ Wc via one-K-step MFMA (real K=6, padded to 32)
      f32x4 accr[2][4] = {};
      {
        bf16x8 a0 = *(const bf16x8*)(rbfA + (mb + l16) * 40 + q * 8);
        bf16x8 a1 = *(const bf16x8*)(rbfA + (mb + 16 + l16) * 40 + q * 8);
#pragma unroll
        for (int tj = 0; tj < 4; ++tj) {
          bf16x8 b = *(const bf16x8*)(Wcb + (nb + tj * 16 + l16) * 40 + q * 8);
          accr[0][tj] = __builtin_amdgcn_mfma_f32_16x16x32_bf16(a0, b, accr[0][tj], 0, 0, 0);
          accr[1][tj] = __builtin_amdgcn_mfma_f32_16x16x32_bf16(a1, b, accr[1][tj], 0, 0, 0);
        }
      }
      // tmp = silu(x@Wkj + b) * rbf_p  -> swizzled A-layout in tmpA
#pragma unroll
      for (int ti = 0; ti < 2; ++ti)
#pragma unroll
        for (int r = 0; r < 4; ++r) {
          const int row = mb + ti * 16 + q * 4 + r;
#pragma unroll
          for (int gl = 0; gl < 2; ++gl) {
            const int col0 = nb + gl * 32 + 2 * l16;
            const float2 b2 = *(const float2*)&biasS[col0];
            const float v0 = silu_f(acc[ti][2 * gl][r] + b2.x) * accr[ti][2 * gl][r];
            const float v1 = silu_f(acc[ti][2 * gl + 1][r] + b2.y) * accr[ti][2 * gl + 1][r];
            *(uint32_t*)&tmpA[(row << 7) + ((((col0 >> 3) ^ (row & 15)) << 3) | (col0 & 7))] =
                pack_bf16(v0, v1);
          }
        }
      __syncthreads();   // tmpA complete

      const int nb2 = (wv & 1) * 32;
      f32x4 acc2[2][2] = {};
      gemm_tile<4, 2>(tmpA, Wdn, mb, nb2, l16, q, acc2);
#pragma unroll
      for (int ti = 0; ti < 2; ++ti)
#pragma unroll
        for (int r = 0; r < 4; ++r) {
          const int row = mb + ti * 16 + q * 4 + r;
          const int col0 = nb2 + 2 * l16;
          *(uint32_t*)&down[((size_t)(br - 1) * E_N + R + row) * 64 + col0] =
              pack_bf16(silu_f(acc2[ti][0][r]), silu_f(acc2[ti][1][r]));
        }
    }

    VMCNT0();          // drains epilogue stores + next set's prefetch (already landed)
    __syncthreads();   // all waves done reading this slot
    if (br < 4)
      dma_copy<60>(esets + (size_t)(br + 2) * ESET_BYTES, (char*)Wset[br & 1], wv, lane);
  }
}

// =====================  K2: triplet c8 projection + CSR bucket build  =====================
__global__ __launch_bounds__(256, 4)
void c8_kernel(const float* __restrict__ sbf, const int* __restrict__ idx_kj,
               const int* __restrict__ idx_ji, const int* __restrict__ bt,
               const float* __restrict__ Wsbf1,
               float* __restrict__ c8g, uint32_t* __restrict__ meta,
               int* __restrict__ cnt, int* __restrict__ list,
               int* __restrict__ ovf)   // ovf[0]=count, pairs (t,ji) from ovf[2]
{
  __shared__ float s_sbf[64 * 44];
  __shared__ float s_W1[2016];   // [6][42][8]
  __shared__ float s_c8[64 * 16];
  __shared__ int s_bs[64];

  const int tid = threadIdx.x;
  const int base = blockIdx.x * 64;

  for (int i = tid; i < 2016; i += 256) s_W1[i] = Wsbf1[i];
  if (tid < 64) {
    const int t = base + tid;
    const int kj = idx_kj[t];
    const int ji = idx_ji[t];
    const int bs = bt[kj] + 1;   // BT_LIST[b] = b-1 for b>=1; bt in [0,5)
    s_bs[tid] = bs;
    meta[t] = (uint32_t)kj | ((uint32_t)bs << 16);
    const int pos = atomicAdd(&cnt[ji], 1);
    if (pos < CAP) {
      list[ji * CAP + pos] = t;
    } else {
      const int o = atomicAdd(&ovf[0], 1);
      if (o < OVF_MAX) { ovf[2 + 2 * o] = t; ovf[2 + 2 * o + 1] = ji; }
    }
  }
  {
    const float2* sg = (const float2*)(sbf + (size_t)base * 42);
    for (int i = tid; i < 64 * 21; i += 256) {
      const int r = i / 21, c2 = i - r * 21;
      const float2 v = sg[i];
      s_sbf[r * 44 + c2 * 2] = v.x;
      s_sbf[r * 44 + c2 * 2 + 1] = v.y;
    }
  }
  __syncthreads();

  { // c8[i][brr*8+c] : brr=0 -> branch 5, brr=1 -> branch bs
    const int i = tid >> 2;
    const int brr = (tid >> 1) & 1;
    const int cg = tid & 1;
    const int b = brr ? s_bs[i] : 5;
    const float* w = &s_W1[b * 336 + cg * 4];
    const float* sb = &s_sbf[i * 44];
    float a0 = 0.f, a1 = 0.f, a2 = 0.f, a3 = 0.f;
#pragma unroll
    for (int s = 0; s < 42; ++s) {
      const float sv = sb[s];
      const float* ws = w + s * 8;
      a0 += sv * ws[0]; a1 += sv * ws[1]; a2 += sv * ws[2]; a3 += sv * ws[3];
    }
    float* dc = &s_c8[i * 16 + brr * 8 + cg * 4];
    dc[0] = a0; dc[1] = a1; dc[2] = a2; dc[3] = a3;
  }
  __syncthreads();

  { // coalesced write-out: 256 threads x float4 = 64 triplets x 16 floats
    const float4* s4 = (const float4*)s_c8;
    float4* g4 = (float4*)(c8g + (size_t)base * 16);
    g4[tid] = s4[tid];
  }
}

// =====================  K3: per-edge gather (no atomics)  =====================
__global__ __launch_bounds__(256, 8)
void gather_kernel(const int* __restrict__ cnt, const int* __restrict__ list,
                   const uint32_t* __restrict__ meta, const float* __restrict__ c8g,
                   const float* __restrict__ Wsbf2, const bf16_t* __restrict__ down,
                   const float* __restrict__ alpha_p, const int* __restrict__ ovf,
                   float* __restrict__ xkj)
{
  __shared__ float sW2[3072];   // [6][8][64]
  for (int i = threadIdx.x; i < 3072; i += 256) sW2[i] = Wsbf2[i];
  __syncthreads();

  const int e = blockIdx.x * 4 + (threadIdx.x >> 6);
  const int j = threadIdx.x & 63;
  const float alpha = alpha_p[0], oma = 1.f - alpha;
  const float* w5 = &sW2[5 * 512 + j];

  float acc = 0.f;
  int n = cnt[e];
  if (n > CAP) n = CAP;
#pragma unroll 2
  for (int k = 0; k < n; ++k) {
    const int t = __builtin_amdgcn_readfirstlane(list[e * CAP + k]);
    const uint32_t m = __builtin_amdgcn_readfirstlane(meta[t]);
    const int kj = m & 0xffff;
    const int b  = m >> 16;
    const float g5 = (float)down[((size_t)4 * E_N + kj) * 64 + j];
    const float gb = (float)down[((size_t)(b - 1) * E_N + kj) * 64 + j];
    const float* cp = c8g + (size_t)t * 16;
    float d5 = 0.f, db = 0.f;
#pragma unroll
    for (int c = 0; c < 8; ++c) {
      d5 += cp[c]     * w5[c * 64];
      db += cp[8 + c] * sW2[b * 512 + c * 64 + j];
    }
    acc += alpha * g5 * d5 + oma * gb * db;
  }

  const int oc = ovf[0];       // normally 0; full correctness fallback
  for (int k = 0; k < oc; ++k) {
    const int ji = ovf[2 + 2 * k + 1];
    if (ji != e) continue;
    const int t = ovf[2 + 2 * k];
    const uint32_t m = meta[t];
    const int kj = m & 0xffff;
    const int b  = m >> 16;
    const float g5 = (float)down[((size_t)4 * E_N + kj) * 64 + j];
    const float gb = (float)down[((size_t)(b - 1) * E_N + kj) * 64 + j];
    const float* cp = c8g + (size_t)t * 16;
    float d5 = 0.f, db = 0.f;
#pragma unroll
    for (int c = 0; c < 8; ++c) {
      d5 += cp[c]     * w5[c * 64];
      db += cp[8 + c] * sW2[b * 512 + c * 64 + j];
    }
    acc += alpha * g5 * d5 + oma * gb * db;
  }

  xkj[(size_t)e * 64 + j] = acc;
}

// =====================  K4: fused epilogue chain (DMA-prefetched weights)  =====================
__global__ __launch_bounds__(256, 1)
void epi_kernel(const float* __restrict__ x, const bf16_t* __restrict__ x_ji,
                const float* __restrict__ xkj, const char* __restrict__ psets,
                float* __restrict__ out)
{
  __shared__ __align__(16) bf16_t bufA[64 * 128];
  __shared__ __align__(16) bf16_t bufB[64 * 128];
  __shared__ __align__(16) char Wset[2][PSET_BYTES];   // total 106496 B

  const int tid = threadIdx.x;
  const int lane = tid & 63, wv = tid >> 6;
  const int q = lane >> 4, l16 = lane & 15;
  const int mb = (wv >> 1) * 32, nb = (wv & 1) * 64;
  const int R = blockIdx.x * 64;

  stage_x<16>(bufA, xkj + (size_t)R * 64, tid);
  VMCNT0();
  dma_copy<36>(psets,              (char*)Wset[0], wv, lane);
  dma_copy<36>(psets + PSET_BYTES, (char*)Wset[1], wv, lane);
  asm volatile("s_waitcnt vmcnt(9)" ::: "memory");
  __syncthreads();

  f32x4 hreg[2][4];
  { // stage 0: h = x_ji + silu(xkj @ W_up)  -> bufB
    f32x4 acc[2][4] = {};
    gemm_tile<2, 4>(bufA, (const bf16_t*)Wset[0], mb, nb, l16, q, acc);
#pragma unroll
    for (int ti = 0; ti < 2; ++ti)
#pragma unroll
      for (int r = 0; r < 4; ++r) {
        const int row = mb + ti * 16 + q * 4 + r;
#pragma unroll
        for (int gl = 0; gl < 2; ++gl) {
          const int col0 = nb + gl * 32 + 2 * l16;
          union { uint32_t u; bf16x2 h; } xj;
          xj.u = *(const uint32_t*)&x_ji[(size_t)(R + row) * 128 + col0];
          const float h0 = (float)xj.h[0] + silu_f(acc[ti][2 * gl][r]);
          const float h1 = (float)xj.h[1] + silu_f(acc[ti][2 * gl + 1][r]);
          hreg[ti][2 * gl][r] = h0;
          hreg[ti][2 * gl + 1][r] = h1;
          *(uint32_t*)&bufB[(row << 7) + ((((col0 >> 3) ^ (row & 15)) << 3) | (col0 & 7))] =
              pack_bf16(h0, h1);
        }
      }
  }
  VMCNT0();
  __syncthreads();
  dma_copy<36>(psets + 2 * PSET_BYTES, (char*)Wset[0], wv, lane);

#define EPI_STAGE(K, ASRC, BODY)                                                 \
  {                                                                              \
    const char* slot_ = Wset[(K) & 1];                                           \
    const float* biasS = (const float*)(slot_ + 32768);                          \
    f32x4 acc[2][4] = {};                                                        \
    gemm_tile<4, 4>(ASRC, (const bf16_t*)slot_, mb, nb, l16, q, acc);            \
    _Pragma("unroll")                                                            \
    for (int ti = 0; ti < 2; ++ti)                                               \
      _Pragma("unroll")                                                          \
      for (int r = 0; r < 4; ++r) {                                              \
        const int row = mb + ti * 16 + q * 4 + r;                                \
        _Pragma("unroll")                                                        \
        for (int gl = 0; gl < 2; ++gl) {                                         \
          const int col0 = nb + gl * 32 + 2 * l16;                               \
          const float2 b2 = *(const float2*)&biasS[col0];                        \
          const float g0 = acc[ti][2 * gl][r] + b2.x;                            \
          const float g1 = acc[ti][2 * gl + 1][r] + b2.y;                        \
          BODY                                                                   \
        }                                                                        \
      }                                                                          \
  }                                                                              \
  VMCNT0();                                                                      \
  __syncthreads();                                                               \
  if ((K) + 2 <= 5)                                                              \
    dma_copy<36>(psets + ((K) + 2) * PSET_BYTES, (char*)Wset[(K) & 1], wv, lane);

  // stage 1: u = silu(h @ rb1 + b) -> bufA
  EPI_STAGE(1, bufB, {
    *(uint32_t*)&bufA[(row << 7) + ((((col0 >> 3) ^ (row & 15)) << 3) | (col0 & 7))] =
        pack_bf16(silu_f(g0), silu_f(g1));
  })

  // stage 2: h += silu(u @ rb2 + b) -> bufB
  EPI_STAGE(2, bufA, {
    const float h0 = hreg[ti][2 * gl][r] + silu_f(g0);
    const float h1 = hreg[ti][2 * gl + 1][r] + silu_f(g1);
    hreg[ti][2 * gl][r] = h0; hreg[ti][2 * gl + 1][r] = h1;
    *(uint32_t*)&bufB[(row << 7) + ((((col0 >> 3) ^ (row & 15)) << 3) | (col0 & 7))] =
        pack_bf16(h0, h1);
  })

  // stage 3: h = silu(h @ W_lin + b) + x -> bufA
  EPI_STAGE(3, bufB, {
    const float2 xv = *(const float2*)&x[(size_t)(R + row) * 128 + col0];
    const float h0 = silu_f(g0) + xv.x;
    const float h1 = silu_f(g1) + xv.y;
    hreg[ti][2 * gl][r] = h0; hreg[ti][2 * gl + 1][r] = h1;
    *(uint32_t*)&bufA[(row << 7) + ((((col0 >> 3) ^ (row & 15)) << 3) | (col0 & 7))] =
        pack_bf16(h0, h1);
  })

  // stage 4: u = silu(h @ ra1 + b) -> bufB
  EPI_STAGE(4, bufA, {
    *(uint32_t*)&bufB[(row << 7) + ((((col0 >> 3) ^ (row & 15)) << 3) | (col0 & 7))] =
        pack_bf16(silu_f(g0), silu_f(g1));
  })

  // stage 5: out = h + silu(u @ ra2 + b)
  EPI_STAGE(5, bufB, {
    float2 o;
    o.x = hreg[ti][2 * gl][r] + silu_f(g0);
    o.y = hreg[ti][2 * gl + 1][r] + silu_f(g1);
    *(float2*)&out[(size_t)(R + row) * 128 + col0] = o;
  })
#undef EPI_STAGE
}

extern "C" void kernel_launch(void* const* d_in, const int* in_sizes, int n_in,
                              void* d_out, int out_size, void* d_ws, size_t ws_size,
                              hipStream_t stream)
{
  (void)in_sizes; (void)n_in; (void)out_size; (void)ws_size;
  const float* x      = (const float*)d_in[0];
  const float* rbf    = (const float*)d_in[1];
  const float* sbf    = (const float*)d_in[2];
  const int*   idx_kj = (const int*)d_in[3];
  const int*   idx_ji = (const int*)d_in[4];
  const int*   bt     = (const int*)d_in[5];
  const float* alpha  = (const float*)d_in[7];
  const float* W_kj   = (const float*)d_in[8];
  const float* b_kj   = (const float*)d_in[9];
  const float* W_rbf1 = (const float*)d_in[10];
  const float* W_rbf2 = (const float*)d_in[11];
  const float* W_sbf1 = (const float*)d_in[12];
  const float* W_sbf2 = (const float*)d_in[13];
  const float* W_down = (const float*)d_in[14];
  const float* W_ji   = (const float*)d_in[15];
  const float* b_ji   = (const float*)d_in[16];
  const float* W_up   = (const float*)d_in[17];
  const float* rb1_w  = (const float*)d_in[18];
  const float* rb1_b  = (const float*)d_in[19];
  const float* rb2_w  = (const float*)d_in[20];
  const float* rb2_b  = (const float*)d_in[21];
  const float* W_lin  = (const float*)d_in[22];
  const float* b_lin  = (const float*)d_in[23];
  const float* ra1_w  = (const float*)d_in[24];
  const float* ra1_b  = (const float*)d_in[25];
  const float* ra2_w  = (const float*)d_in[26];
  const float* ra2_b  = (const float*)d_in[27];

  char* ws = (char*)d_ws;
  bf16_t* down   = (bf16_t*)(ws);                 // 5*E*64*2  = 41,943,040
  bf16_t* x_ji   = (bf16_t*)(ws + 41943040);      // E*128*2   = 16,777,216
  float*  xkj    = (float*) (ws + 58720256);      // E*64*4    = 16,777,216
  char*   esets  = ws + 75497472;                 // 6*61440   =    368,640
  char*   psets  = ws + 75866112;                 // 6*36864   =    221,184
  float*    c8g  = (float*)   (ws + 76087296);    // T*16*4    = 16,777,216
  uint32_t* meta = (uint32_t*)(ws + 92864512);    // T*4       =  1,048,576
  int*      list = (int*)     (ws + 93913088);    // E*CAP*4   =  4,194,304
  int*      cnt  = (int*)     (ws + 98107392);    // E*4       =    262,144
  int*      ovf  = (int*)     (ws + 98369536);    // 8 + 2*T*4 =  2,097,160

  hipMemsetAsync(cnt, 0, 262144 + 8, stream);     // cnt + ovf[0..1]
  prep_kernel<<<116, 256, 0, stream>>>(W_ji, W_kj, W_down, W_up, rb1_w, rb2_w,
                                       W_lin, ra1_w, ra2_w, W_rbf1, W_rbf2,
                                       b_ji, b_kj, rb1_b, rb2_b, b_lin,
                                       ra1_b, ra2_b, esets, psets);
  edge_kernel<<<E_N / 64, 256, 0, stream>>>(x, rbf, esets, x_ji, down);
  c8_kernel<<<T_N / 64, 256, 0, stream>>>(sbf, idx_kj, idx_ji, bt, W_sbf1,
                                          c8g, meta, cnt, list, ovf);
  gather_kernel<<<E_N / 4 / 64, 256, 0, stream>>>(cnt, list, meta, c8g, W_sbf2,
                                                  down, alpha, ovf, xkj);
  epi_kernel<<<E_N / 64, 256, 0, stream>>>(x, x_ji, xkj, psets, (float*)d_out);
}